// Round 10
// baseline (2461.410 us; speedup 1.0000x reference)
//
#include <hip/hip_runtime.h>
#include <cstdint>
#include <cstddef>

// ---------------------------------------------------------------------------
// EdgeCNN (DGCNN) 3-layer network.
//   Factorization: concat[x_i, x_j-x_i] @ W1 = x_i@(W1a-W1b) + x_j@W1b
//   => per-layer: node GEMM makes A = h@(W1a-W1b)+b1, B = h@W1b (stored bf16);
//      per-edge:  msg = ReLU(A[dst]+B[src]) @ W2 + b2; atomic-max into agg[dst].
// Segment-max via order-preserving float->u32 key + atomicMax (deterministic).
// Workspace budget kept < 53 MB: R7 post-mortem attributed post-timing
// divergence to ws overflow (78 MB layout) corrupting harness pristine copies.
// ---------------------------------------------------------------------------

#define KEY_NEGINF 0x007FFFFFu  // fkey(-inf)

__device__ __forceinline__ unsigned fkey(float f) {
  unsigned u = __float_as_uint(f);
  return (u & 0x80000000u) ? ~u : (u | 0x80000000u);
}
__device__ __forceinline__ float funkey(unsigned k) {
  unsigned u = (k & 0x80000000u) ? (k & 0x7FFFFFFFu) : ~k;
  return __uint_as_float(u);
}
// fp32 -> bf16 (RNE) and bf16 -> fp32 (exact)
__device__ __forceinline__ unsigned short f2bf(float f) {
  unsigned u = __float_as_uint(f);
  unsigned r = u + 0x7FFFu + ((u >> 16) & 1u);
  return (unsigned short)(r >> 16);
}
__device__ __forceinline__ float bflo(unsigned u) { return __uint_as_float(u << 16); }
__device__ __forceinline__ float bfhi(unsigned u) { return __uint_as_float(u & 0xFFFF0000u); }

// wcat[k][o]   = w1[k][o] - w1[(F+k)][o]   (o in [0,O))
// wcat[k][O+o] = w1[(F+k)][o]
__global__ void build_wcat(const float* __restrict__ w1, float* __restrict__ wcat,
                           int F, int O) {
  int i = blockIdx.x * 256 + threadIdx.x;
  int total = F * O;
  if (i >= total) return;
  int k = i / O, o = i - k * O;
  float wa = w1[(size_t)k * O + o];
  float wb = w1[(size_t)(F + k) * O + o];
  wcat[(size_t)k * 2 * O + o] = wa - wb;
  wcat[(size_t)k * 2 * O + O + o] = wb;
}

__global__ void fill_u32(unsigned* __restrict__ p, unsigned v, size_t n) {
  size_t i = (size_t)blockIdx.x * blockDim.x + threadIdx.x;
  size_t stride = (size_t)gridDim.x * blockDim.x;
  for (; i < n; i += stride) p[i] = v;
}

// decode keys -> float, fold (neg-inf -> 0) and inter-layer ReLU: out = max(val, 0)
__global__ void decode_relu(unsigned* __restrict__ p, size_t n) {
  size_t i = (size_t)blockIdx.x * blockDim.x + threadIdx.x;
  size_t stride = (size_t)gridDim.x * blockDim.x;
  float* pf = reinterpret_cast<float*>(p);
  for (; i < n; i += stride) {
    float v = funkey(p[i]);
    pf[i] = fmaxf(v, 0.0f);
  }
}

__global__ void final_out(const unsigned* __restrict__ p, float* __restrict__ out, size_t n) {
  size_t i = (size_t)blockIdx.x * blockDim.x + threadIdx.x;
  size_t stride = (size_t)gridDim.x * blockDim.x;
  for (; i < n; i += stride) {
    unsigned k = p[i];
    out[i] = (k == KEY_NEGINF) ? 0.0f : funkey(k);
  }
}

// hin [N,128] fp32 @ wcat [128,256] -> Abf [N,128] bf16 (cols 0..127, +bias),
//                                      Bbf [N,128] bf16 (cols 128..255)
__global__ __launch_bounds__(256, 2) void node_gemm(
    const float* __restrict__ hin, const float* __restrict__ wcat,
    const float* __restrict__ bias, unsigned short* __restrict__ Abf,
    unsigned short* __restrict__ Bbf, int nNodes) {
  __shared__ float xt[64][132];   // 64 nodes x K=128 (row = 528B, 16B-aligned)
  __shared__ float wt[32][256];   // K-chunk of wcat
  int t = threadIdx.x;
  int m_base = blockIdx.x * 64;

  {  // stage x tile: 4 threads/row, 8 float4 each
    int r = t >> 2, q = t & 3;
    int gm = m_base + r;
    const float4* src = reinterpret_cast<const float4*>(hin + (size_t)gm * 128);
    #pragma unroll
    for (int j = 0; j < 8; ++j) {
      int c4 = q + 4 * j;
      float4 v = make_float4(0.f, 0.f, 0.f, 0.f);
      if (gm < nNodes) v = src[c4];
      *reinterpret_cast<float4*>(&xt[r][c4 * 4]) = v;
    }
  }

  float acc[8][8];
  #pragma unroll
  for (int i = 0; i < 8; ++i)
    #pragma unroll
    for (int j = 0; j < 8; ++j) acc[i][j] = 0.f;

  int m0 = (t >> 5) * 8;   // 0..56
  int c0 = (t & 31) * 8;   // 0..248

  for (int kc = 0; kc < 128; kc += 32) {
    __syncthreads();  // protect wt (and xt on first iter)
    #pragma unroll
    for (int j = 0; j < 8; ++j) {
      int idx = t + 256 * j;  // float4 index into 32x256 chunk
      reinterpret_cast<float4*>(&wt[0][0])[idx] =
          reinterpret_cast<const float4*>(wcat + (size_t)kc * 256)[idx];
    }
    __syncthreads();
    #pragma unroll 4
    for (int k = 0; k < 32; ++k) {
      float xv[8];
      #pragma unroll
      for (int i = 0; i < 8; ++i) xv[i] = xt[m0 + i][kc + k];
      float4 w0 = *reinterpret_cast<float4*>(&wt[k][c0]);
      float4 w1 = *reinterpret_cast<float4*>(&wt[k][c0 + 4]);
      #pragma unroll
      for (int i = 0; i < 8; ++i) {
        acc[i][0] += xv[i] * w0.x; acc[i][1] += xv[i] * w0.y;
        acc[i][2] += xv[i] * w0.z; acc[i][3] += xv[i] * w0.w;
        acc[i][4] += xv[i] * w1.x; acc[i][5] += xv[i] * w1.y;
        acc[i][6] += xv[i] * w1.z; acc[i][7] += xv[i] * w1.w;
      }
    }
  }

  bool isA = (c0 < 128);
  float bv[8];
  #pragma unroll
  for (int j = 0; j < 8; ++j) bv[j] = isA ? bias[c0 + j] : 0.f;
  #pragma unroll
  for (int i = 0; i < 8; ++i) {
    int gm = m_base + m0 + i;
    if (gm >= nNodes) continue;
    alignas(16) unsigned short ob[8];
    #pragma unroll
    for (int j = 0; j < 8; ++j) ob[j] = f2bf(acc[i][j] + bv[j]);
    unsigned short* dst = isA ? (Abf + (size_t)gm * 128 + c0)
                              : (Bbf + (size_t)gm * 128 + (c0 - 128));
    *reinterpret_cast<uint4*>(dst) = *reinterpret_cast<const uint4*>(ob);
  }
}

// Per-edge: h = ReLU(A[dst]+B[src]) (bf16 gather -> fp32); msg = h @ W2 + b2;
// atomicMax keys into aggk[dst]. Tile = 64 edges; W2 staged in 2 K-chunks.
__global__ __launch_bounds__(256, 2) void edge_gemm(
    const unsigned short* __restrict__ Abf, const unsigned short* __restrict__ Bbf,
    const int* __restrict__ ei,  // [2][E] int32
    const float* __restrict__ W2, const float* __restrict__ b2,
    unsigned* __restrict__ aggk, int E_) {
  __shared__ float ht[64][132];
  __shared__ float wt[64][128];
  __shared__ int dstl[64];
  int t = threadIdx.x;
  int e_base = blockIdx.x * 64;

  if (t < 64) {
    int e = min(e_base + t, E_ - 1);
    dstl[t] = ei[E_ + e];
  }
  {  // build h tile: 4 threads/row, bf16 gather (16B = 8 bf16 per chunk)
    int r = t >> 2, q = t & 3;
    int e = min(e_base + r, E_ - 1);
    int s = ei[e];
    int d = ei[E_ + e];
    const uint4* Ar = reinterpret_cast<const uint4*>(Abf + (size_t)d * 128);
    const uint4* Br = reinterpret_cast<const uint4*>(Bbf + (size_t)s * 128);
    #pragma unroll
    for (int j = 0; j < 4; ++j) {
      int c8 = q + 4 * j;  // chunk of 8 bf16, 0..15
      uint4 a = Ar[c8], b = Br[c8];
      float4 h0, h1;
      h0.x = fmaxf(bflo(a.x) + bflo(b.x), 0.f);
      h0.y = fmaxf(bfhi(a.x) + bfhi(b.x), 0.f);
      h0.z = fmaxf(bflo(a.y) + bflo(b.y), 0.f);
      h0.w = fmaxf(bfhi(a.y) + bfhi(b.y), 0.f);
      h1.x = fmaxf(bflo(a.z) + bflo(b.z), 0.f);
      h1.y = fmaxf(bfhi(a.z) + bfhi(b.z), 0.f);
      h1.z = fmaxf(bflo(a.w) + bflo(b.w), 0.f);
      h1.w = fmaxf(bfhi(a.w) + bfhi(b.w), 0.f);
      *reinterpret_cast<float4*>(&ht[r][c8 * 8]) = h0;
      *reinterpret_cast<float4*>(&ht[r][c8 * 8 + 4]) = h1;
    }
  }

  float acc[8][4];
  #pragma unroll
  for (int i = 0; i < 8; ++i)
    #pragma unroll
    for (int j = 0; j < 4; ++j) acc[i][j] = 0.f;

  int e0 = (t >> 5) * 8;   // 0..56
  int c0 = (t & 31) * 4;   // 0..124

  for (int kc = 0; kc < 128; kc += 64) {
    __syncthreads();  // protects ht on first iter, wt on both
    #pragma unroll
    for (int j = 0; j < 8; ++j) {
      int idx = t + 256 * j;  // float4 index into 64x128 chunk
      reinterpret_cast<float4*>(&wt[0][0])[idx] =
          reinterpret_cast<const float4*>(W2 + (size_t)kc * 128)[idx];
    }
    __syncthreads();
    #pragma unroll 4
    for (int k = 0; k < 64; ++k) {
      float4 w = *reinterpret_cast<float4*>(&wt[k][c0]);
      float hv[8];
      #pragma unroll
      for (int i = 0; i < 8; ++i) hv[i] = ht[e0 + i][kc + k];
      #pragma unroll
      for (int i = 0; i < 8; ++i) {
        acc[i][0] += hv[i] * w.x;
        acc[i][1] += hv[i] * w.y;
        acc[i][2] += hv[i] * w.z;
        acc[i][3] += hv[i] * w.w;
      }
    }
  }

  float4 bb = *reinterpret_cast<const float4*>(b2 + c0);
  #pragma unroll
  for (int i = 0; i < 8; ++i) {
    int d = dstl[e0 + i];
    unsigned* p = aggk + (size_t)d * 128 + c0;
    atomicMax(p + 0, fkey(acc[i][0] + bb.x));
    atomicMax(p + 1, fkey(acc[i][1] + bb.y));
    atomicMax(p + 2, fkey(acc[i][2] + bb.z));
    atomicMax(p + 3, fkey(acc[i][3] + bb.w));
  }
}

// Layer 2 node linear: hin [N,128] fp32 @ wcat2 [128,4] -> AB2 [N,4]
// cols 0,1 = A2 (+b1), cols 2,3 = B2
__global__ void node_thin(const float* __restrict__ hin, const float* __restrict__ wcat2,
                          const float* __restrict__ b1, float* __restrict__ AB2,
                          int nNodes) {
  __shared__ float w[128 * 4];
  int t = threadIdx.x;
  if (t < 128) *reinterpret_cast<float4*>(&w[t * 4]) =
      reinterpret_cast<const float4*>(wcat2)[t];
  __syncthreads();
  int node = blockIdx.x * 64 + (t >> 2);
  int o = t & 3;
  if (node >= nNodes) return;
  const float4* h4 = reinterpret_cast<const float4*>(hin + (size_t)node * 128);
  float acc = 0.f;
  #pragma unroll 8
  for (int kk = 0; kk < 32; ++kk) {
    float4 x = h4[kk];
    acc += x.x * w[(kk * 4 + 0) * 4 + o];
    acc += x.y * w[(kk * 4 + 1) * 4 + o];
    acc += x.z * w[(kk * 4 + 2) * 4 + o];
    acc += x.w * w[(kk * 4 + 3) * 4 + o];
  }
  if (o < 2) acc += b1[o];
  AB2[(size_t)node * 4 + o] = acc;
}

__global__ void edge_small(const float* __restrict__ AB2, const int* __restrict__ ei,
                           const float* __restrict__ w2, const float* __restrict__ b2,
                           unsigned* __restrict__ aggk2, int E_) {
  int e = blockIdx.x * 256 + threadIdx.x;
  if (e >= E_) return;
  int s = ei[e];
  int d = ei[E_ + e];
  float2 a = *reinterpret_cast<const float2*>(AB2 + (size_t)d * 4);
  float2 b = *reinterpret_cast<const float2*>(AB2 + (size_t)s * 4 + 2);
  float h0 = fmaxf(a.x + b.x, 0.f);
  float h1 = fmaxf(a.y + b.y, 0.f);
  float m0 = h0 * w2[0] + h1 * w2[2] + b2[0];
  float m1 = h0 * w2[1] + h1 * w2[3] + b2[1];
  atomicMax(aggk2 + (size_t)d * 2 + 0, fkey(m0));
  atomicMax(aggk2 + (size_t)d * 2 + 1, fkey(m1));
}

extern "C" void kernel_launch(void* const* d_in, const int* in_sizes, int n_in,
                              void* d_out, int out_size, void* d_ws, size_t ws_size,
                              hipStream_t stream) {
  const float* x    = (const float*)d_in[0];
  const int*   ei   = (const int*)d_in[1];
  const float* w1_0 = (const float*)d_in[2];
  const float* b1_0 = (const float*)d_in[3];
  const float* w2_0 = (const float*)d_in[4];
  const float* b2_0 = (const float*)d_in[5];
  const float* w1_1 = (const float*)d_in[6];
  const float* b1_1 = (const float*)d_in[7];
  const float* w2_1 = (const float*)d_in[8];
  const float* b2_1 = (const float*)d_in[9];
  const float* w1_2 = (const float*)d_in[10];
  const float* b1_2 = (const float*)d_in[11];
  const float* w2_2 = (const float*)d_in[12];
  const float* b2_2 = (const float*)d_in[13];

  const int N = in_sizes[0] / 128;
  const int E = in_sizes[1] / 2;

  // Workspace layout (total ~52.7 MB for N=50000):
  //   Z    [N*128] u32/f32  25.6 MB   agg keys, then decoded h
  //   Abf  [N*128] bf16     12.8 MB
  //   Bbf  [N*128] bf16     12.8 MB
  //   AB2  [N*4]   f32       0.8 MB
  //   agg2 [N*2]   u32       0.4 MB
  //   wc0,wc1 [128*256] f32  0.26 MB  wc2 [128*4] f32
  char* ws = (char*)d_ws;
  const size_t NB = (size_t)N * 128 * 4;
  const size_t HB = (size_t)N * 128 * 2;
  unsigned*       Z    = (unsigned*)(ws);
  unsigned short* Abf  = (unsigned short*)(ws + NB);
  unsigned short* Bbf  = (unsigned short*)(ws + NB + HB);
  float*    AB2  = (float*)(ws + NB + 2 * HB);
  unsigned* agg2 = (unsigned*)(ws + NB + 2 * HB + (size_t)N * 16);
  float*    wc0  = (float*)(ws + NB + 2 * HB + (size_t)N * 16 + (size_t)N * 8);
  float*    wc1  = wc0 + 128 * 256;
  float*    wc2  = wc1 + 128 * 256;

  const int nb = (N + 63) / 64;
  const int eb = (E + 63) / 64;
  const size_t nH = (size_t)N * 128;

  build_wcat<<<64, 256, 0, stream>>>(w1_0, wc0, 128, 128);
  build_wcat<<<64, 256, 0, stream>>>(w1_1, wc1, 128, 128);
  build_wcat<<<1, 256, 0, stream>>>(w1_2, wc2, 128, 2);

  // layer 0
  node_gemm<<<nb, 256, 0, stream>>>(x, wc0, b1_0, Abf, Bbf, N);
  fill_u32<<<1024, 256, 0, stream>>>(Z, KEY_NEGINF, nH);
  edge_gemm<<<eb, 256, 0, stream>>>(Abf, Bbf, ei, w2_0, b2_0, Z, E);
  decode_relu<<<1024, 256, 0, stream>>>(Z, nH);

  // layer 1
  node_gemm<<<nb, 256, 0, stream>>>((const float*)Z, wc1, b1_1, Abf, Bbf, N);
  fill_u32<<<1024, 256, 0, stream>>>(Z, KEY_NEGINF, nH);
  edge_gemm<<<eb, 256, 0, stream>>>(Abf, Bbf, ei, w2_1, b2_1, Z, E);
  decode_relu<<<1024, 256, 0, stream>>>(Z, nH);

  // layer 2
  node_thin<<<nb, 256, 0, stream>>>((const float*)Z, wc2, b1_2, AB2, N);
  fill_u32<<<256, 256, 0, stream>>>(agg2, KEY_NEGINF, (size_t)N * 2);
  edge_small<<<(E + 255) / 256, 256, 0, stream>>>(AB2, ei, w2_2, b2_2, agg2, E);
  final_out<<<((size_t)N * 2 + 255) / 256, 256, 0, stream>>>(agg2, (float*)d_out, (size_t)N * 2);
}

// Round 12
// 865.260 us; speedup vs baseline: 2.8447x; 2.8447x over previous
//
#include <hip/hip_runtime.h>
#include <cstdint>
#include <cstddef>

// ---------------------------------------------------------------------------
// EdgeCNN (DGCNN) 3-layer network.
//   Factorization: concat[x_i, x_j-x_i] @ W1 = x_i@(W1a-W1b) + x_j@W1b
//   => per-layer: node GEMM makes A = h@(W1a-W1b)+b1, B = h@W1b (stored bf16);
//      per-edge (MFMA): h = ReLU(A[dst]+B[src]) bf16; msg = h @ W2bf + b2;
//      test-before-atomicMax of order-preserving keys into agg[dst].
// R10 counters: old edge_gemm latency-bound (VALUBusy 21.8%, Occ 20.9%,
// 2 blocks/CU @ 67KB LDS) + 1.6GB/dispatch atomic write traffic.
// This round: MFMA tile (48KB LDS -> 3 blocks/CU), 36 ds_read/wave,
// XOR-swizzled LDS (256B rows = 16-way conflict otherwise), agg prefetch
// + conditional atomic. Workspace stays 52.7MB (R7 overflow lesson).
// ---------------------------------------------------------------------------

#define KEY_NEGINF 0x007FFFFFu  // fkey(-inf)

typedef __attribute__((ext_vector_type(8))) short bf16x8;
typedef __attribute__((ext_vector_type(4))) float f32x4;

__device__ __forceinline__ unsigned fkey(float f) {
  unsigned u = __float_as_uint(f);
  return (u & 0x80000000u) ? ~u : (u | 0x80000000u);
}
__device__ __forceinline__ float funkey(unsigned k) {
  unsigned u = (k & 0x80000000u) ? (k & 0x7FFFFFFFu) : ~k;
  return __uint_as_float(u);
}
// fp32 -> bf16 (RNE) and bf16 -> fp32 (exact)
__device__ __forceinline__ unsigned short f2bf(float f) {
  unsigned u = __float_as_uint(f);
  unsigned r = u + 0x7FFFu + ((u >> 16) & 1u);
  return (unsigned short)(r >> 16);
}
__device__ __forceinline__ float bflo(unsigned u) { return __uint_as_float(u << 16); }
__device__ __forceinline__ float bfhi(unsigned u) { return __uint_as_float(u & 0xFFFF0000u); }
// relu(a+b) on two packed bf16 pairs -> packed bf16 pair
__device__ __forceinline__ unsigned pack2(unsigned a, unsigned b) {
  float lo = fmaxf(bflo(a) + bflo(b), 0.f);
  float hi = fmaxf(bfhi(a) + bfhi(b), 0.f);
  return (unsigned)f2bf(lo) | ((unsigned)f2bf(hi) << 16);
}

// wcat[k][o]   = w1[k][o] - w1[(F+k)][o]   (o in [0,O))
// wcat[k][O+o] = w1[(F+k)][o]
__global__ void build_wcat(const float* __restrict__ w1, float* __restrict__ wcat,
                           int F, int O) {
  int i = blockIdx.x * 256 + threadIdx.x;
  int total = F * O;
  if (i >= total) return;
  int k = i / O, o = i - k * O;
  float wa = w1[(size_t)k * O + o];
  float wb = w1[(size_t)(F + k) * O + o];
  wcat[(size_t)k * 2 * O + o] = wa - wb;
  wcat[(size_t)k * 2 * O + O + o] = wb;
}

__global__ void fill_u32(unsigned* __restrict__ p, unsigned v, size_t n) {
  size_t i = (size_t)blockIdx.x * blockDim.x + threadIdx.x;
  size_t stride = (size_t)gridDim.x * blockDim.x;
  for (; i < n; i += stride) p[i] = v;
}

// decode keys -> float, fold (neg-inf -> 0) and inter-layer ReLU: out = max(val, 0)
__global__ void decode_relu(unsigned* __restrict__ p, size_t n) {
  size_t i = (size_t)blockIdx.x * blockDim.x + threadIdx.x;
  size_t stride = (size_t)gridDim.x * blockDim.x;
  float* pf = reinterpret_cast<float*>(p);
  for (; i < n; i += stride) {
    float v = funkey(p[i]);
    pf[i] = fmaxf(v, 0.0f);
  }
}

__global__ void final_out(const unsigned* __restrict__ p, float* __restrict__ out, size_t n) {
  size_t i = (size_t)blockIdx.x * blockDim.x + threadIdx.x;
  size_t stride = (size_t)gridDim.x * blockDim.x;
  for (; i < n; i += stride) {
    unsigned k = p[i];
    out[i] = (k == KEY_NEGINF) ? 0.0f : funkey(k);
  }
}

// hin [N,128] fp32 @ wcat [128,256] -> Abf [N,128] bf16 (cols 0..127, +bias),
//                                      Bbf [N,128] bf16 (cols 128..255)
__global__ __launch_bounds__(256, 2) void node_gemm(
    const float* __restrict__ hin, const float* __restrict__ wcat,
    const float* __restrict__ bias, unsigned short* __restrict__ Abf,
    unsigned short* __restrict__ Bbf, int nNodes) {
  __shared__ float xt[64][132];   // 64 nodes x K=128 (row = 528B, 16B-aligned)
  __shared__ float wt[32][256];   // K-chunk of wcat
  int t = threadIdx.x;
  int m_base = blockIdx.x * 64;

  {  // stage x tile: 4 threads/row, 8 float4 each
    int r = t >> 2, q = t & 3;
    int gm = m_base + r;
    const float4* src = reinterpret_cast<const float4*>(hin + (size_t)gm * 128);
    #pragma unroll
    for (int j = 0; j < 8; ++j) {
      int c4 = q + 4 * j;
      float4 v = make_float4(0.f, 0.f, 0.f, 0.f);
      if (gm < nNodes) v = src[c4];
      *reinterpret_cast<float4*>(&xt[r][c4 * 4]) = v;
    }
  }

  float acc[8][8];
  #pragma unroll
  for (int i = 0; i < 8; ++i)
    #pragma unroll
    for (int j = 0; j < 8; ++j) acc[i][j] = 0.f;

  int m0 = (t >> 5) * 8;   // 0..56
  int c0 = (t & 31) * 8;   // 0..248

  for (int kc = 0; kc < 128; kc += 32) {
    __syncthreads();  // protect wt (and xt on first iter)
    #pragma unroll
    for (int j = 0; j < 8; ++j) {
      int idx = t + 256 * j;  // float4 index into 32x256 chunk
      reinterpret_cast<float4*>(&wt[0][0])[idx] =
          reinterpret_cast<const float4*>(wcat + (size_t)kc * 256)[idx];
    }
    __syncthreads();
    #pragma unroll 4
    for (int k = 0; k < 32; ++k) {
      float xv[8];
      #pragma unroll
      for (int i = 0; i < 8; ++i) xv[i] = xt[m0 + i][kc + k];
      float4 w0 = *reinterpret_cast<float4*>(&wt[k][c0]);
      float4 w1 = *reinterpret_cast<float4*>(&wt[k][c0 + 4]);
      #pragma unroll
      for (int i = 0; i < 8; ++i) {
        acc[i][0] += xv[i] * w0.x; acc[i][1] += xv[i] * w0.y;
        acc[i][2] += xv[i] * w0.z; acc[i][3] += xv[i] * w0.w;
        acc[i][4] += xv[i] * w1.x; acc[i][5] += xv[i] * w1.y;
        acc[i][6] += xv[i] * w1.z; acc[i][7] += xv[i] * w1.w;
      }
    }
  }

  bool isA = (c0 < 128);
  float bv[8];
  #pragma unroll
  for (int j = 0; j < 8; ++j) bv[j] = isA ? bias[c0 + j] : 0.f;
  #pragma unroll
  for (int i = 0; i < 8; ++i) {
    int gm = m_base + m0 + i;
    if (gm >= nNodes) continue;
    alignas(16) unsigned short ob[8];
    #pragma unroll
    for (int j = 0; j < 8; ++j) ob[j] = f2bf(acc[i][j] + bv[j]);
    unsigned short* dst = isA ? (Abf + (size_t)gm * 128 + c0)
                              : (Bbf + (size_t)gm * 128 + (c0 - 128));
    *reinterpret_cast<uint4*>(dst) = *reinterpret_cast<const uint4*>(ob);
  }
}

// MFMA edge kernel: 64 edges/block, 256 threads (4 waves x 16-edge strip).
// LDS: hs [64 rows][128 k] bf16 swizzled (16KB) + wl [128 n][128 k] bf16
// transposed+swizzled (32KB) + dstl -> 48.3KB => 3 blocks/CU.
// Swizzle: 16B chunk index c in row r stored at c^(r&7) (rows are 256B; fixes
// 16-way bank conflict on ds_read_b128 across rows).
__global__ __launch_bounds__(256, 3) void edge_mfma(
    const unsigned short* __restrict__ Abf, const unsigned short* __restrict__ Bbf,
    const int* __restrict__ ei,  // [2][E] int32
    const float* __restrict__ W2, const float* __restrict__ b2,
    unsigned* __restrict__ aggk, int E_) {
  __shared__ unsigned short hs[64 * 128];
  __shared__ unsigned short wl[128 * 128];
  __shared__ int dstl[64];
  int t = threadIdx.x;
  int e_base = blockIdx.x * 64;

  if (t < 64) dstl[t] = ei[E_ + min(e_base + t, E_ - 1)];

  {  // h tile: row r = t>>2 (one edge), 4 chunks of 8 bf16 per thread
    int r = t >> 2, q = t & 3;
    int e = min(e_base + r, E_ - 1);
    int s = ei[e];
    int d = ei[E_ + e];
    const uint4* Ar = reinterpret_cast<const uint4*>(Abf + (size_t)d * 128);
    const uint4* Br = reinterpret_cast<const uint4*>(Bbf + (size_t)s * 128);
    #pragma unroll
    for (int j = 0; j < 4; ++j) {
      int c = q + 4 * j;  // chunk 0..15
      uint4 a = Ar[c], b = Br[c];
      uint4 o;
      o.x = pack2(a.x, b.x);
      o.y = pack2(a.y, b.y);
      o.z = pack2(a.z, b.z);
      o.w = pack2(a.w, b.w);
      *reinterpret_cast<uint4*>(&hs[r * 128 + ((c ^ (r & 7)) * 8)]) = o;
    }
  }
  {  // W2 [k][n] f32 -> wl [n][k] bf16 (transposed), swizzled chunks
    for (int ci = t; ci < 2048; ci += 256) {
      int n = ci & 127, kc = ci >> 7;  // kc: 0..15 (chunk of 8 k)
      alignas(16) unsigned short tmp[8];
      #pragma unroll
      for (int j = 0; j < 8; ++j)
        tmp[j] = f2bf(W2[(size_t)(kc * 8 + j) * 128 + n]);
      *reinterpret_cast<uint4*>(&wl[n * 128 + ((kc ^ (n & 7)) * 8)]) =
          *reinterpret_cast<const uint4*>(tmp);
    }
  }
  __syncthreads();  // only barrier: LDS read-only afterwards

  int l = t & 63;
  int w = t >> 6;
  int strip = w * 16;          // this wave's 16-edge strip
  int lr = l & 15, lh = l >> 4;  // lh in 0..3
  int erow = strip + lh * 4;     // C/D rows this lane owns (+j, j=0..3)

  // prefetch current agg keys (latency hidden under MFMA loop)
  unsigned cur[8][4];
  #pragma unroll
  for (int nt = 0; nt < 8; ++nt) {
    int col = nt * 16 + lr;
    #pragma unroll
    for (int j = 0; j < 4; ++j)
      cur[nt][j] = aggk[(size_t)dstl[erow + j] * 128 + col];
  }

  // A fragments: lane covers edge row strip+lr, k = ks*32 + lh*8 + 0..7
  bf16x8 af[4];
  int arow = strip + lr;
  #pragma unroll
  for (int ks = 0; ks < 4; ++ks) {
    int c = ks * 4 + lh;
    af[ks] = *reinterpret_cast<const bf16x8*>(&hs[arow * 128 + ((c ^ (arow & 7)) * 8)]);
  }

  // MFMA: msg[64 x 128] = h @ W2 ; B-frag: col n = nt*16+lr, same k slice
  f32x4 acc[8];
  #pragma unroll
  for (int nt = 0; nt < 8; ++nt) {
    acc[nt] = (f32x4){0.f, 0.f, 0.f, 0.f};
    int n = nt * 16 + lr;
    #pragma unroll
    for (int ks = 0; ks < 4; ++ks) {
      int c = ks * 4 + lh;
      bf16x8 bf = *reinterpret_cast<const bf16x8*>(&wl[n * 128 + ((c ^ (n & 7)) * 8)]);
      acc[nt] = __builtin_amdgcn_mfma_f32_16x16x32_bf16(af[ks], bf, acc[nt], 0, 0, 0);
    }
  }

  // epilogue: C/D layout col=lane&15, row=(lane>>4)*4+reg (HW-verified)
  #pragma unroll
  for (int nt = 0; nt < 8; ++nt) {
    int col = nt * 16 + lr;
    float bb = b2[col];
    #pragma unroll
    for (int j = 0; j < 4; ++j) {
      unsigned key = fkey(acc[nt][j] + bb);
      if (key > cur[nt][j])
        atomicMax(aggk + (size_t)dstl[erow + j] * 128 + col, key);
    }
  }
}

// Layer 2 node linear: hin [N,128] fp32 @ wcat2 [128,4] -> AB2 [N,4]
// cols 0,1 = A2 (+b1), cols 2,3 = B2
__global__ void node_thin(const float* __restrict__ hin, const float* __restrict__ wcat2,
                          const float* __restrict__ b1, float* __restrict__ AB2,
                          int nNodes) {
  __shared__ float w[128 * 4];
  int t = threadIdx.x;
  if (t < 128) *reinterpret_cast<float4*>(&w[t * 4]) =
      reinterpret_cast<const float4*>(wcat2)[t];
  __syncthreads();
  int node = blockIdx.x * 64 + (t >> 2);
  int o = t & 3;
  if (node >= nNodes) return;
  const float4* h4 = reinterpret_cast<const float4*>(hin + (size_t)node * 128);
  float acc = 0.f;
  #pragma unroll 8
  for (int kk = 0; kk < 32; ++kk) {
    float4 x = h4[kk];
    acc += x.x * w[(kk * 4 + 0) * 4 + o];
    acc += x.y * w[(kk * 4 + 1) * 4 + o];
    acc += x.z * w[(kk * 4 + 2) * 4 + o];
    acc += x.w * w[(kk * 4 + 3) * 4 + o];
  }
  if (o < 2) acc += b1[o];
  AB2[(size_t)node * 4 + o] = acc;
}

__global__ void edge_small(const float* __restrict__ AB2, const int* __restrict__ ei,
                           const float* __restrict__ w2, const float* __restrict__ b2,
                           unsigned* __restrict__ aggk2, int E_) {
  int e = blockIdx.x * 256 + threadIdx.x;
  if (e >= E_) return;
  int s = ei[e];
  int d = ei[E_ + e];
  float2 a = *reinterpret_cast<const float2*>(AB2 + (size_t)d * 4);
  float2 b = *reinterpret_cast<const float2*>(AB2 + (size_t)s * 4 + 2);
  float h0 = fmaxf(a.x + b.x, 0.f);
  float h1 = fmaxf(a.y + b.y, 0.f);
  float m0 = h0 * w2[0] + h1 * w2[2] + b2[0];
  float m1 = h0 * w2[1] + h1 * w2[3] + b2[1];
  atomicMax(aggk2 + (size_t)d * 2 + 0, fkey(m0));
  atomicMax(aggk2 + (size_t)d * 2 + 1, fkey(m1));
}

extern "C" void kernel_launch(void* const* d_in, const int* in_sizes, int n_in,
                              void* d_out, int out_size, void* d_ws, size_t ws_size,
                              hipStream_t stream) {
  const float* x    = (const float*)d_in[0];
  const int*   ei   = (const int*)d_in[1];
  const float* w1_0 = (const float*)d_in[2];
  const float* b1_0 = (const float*)d_in[3];
  const float* w2_0 = (const float*)d_in[4];
  const float* b2_0 = (const float*)d_in[5];
  const float* w1_1 = (const float*)d_in[6];
  const float* b1_1 = (const float*)d_in[7];
  const float* w2_1 = (const float*)d_in[8];
  const float* b2_1 = (const float*)d_in[9];
  const float* w1_2 = (const float*)d_in[10];
  const float* b1_2 = (const float*)d_in[11];
  const float* w2_2 = (const float*)d_in[12];
  const float* b2_2 = (const float*)d_in[13];

  const int N = in_sizes[0] / 128;
  const int E = in_sizes[1] / 2;

  // Workspace layout (total ~52.7 MB for N=50000) — must stay < ws_size (R7).
  char* ws = (char*)d_ws;
  const size_t NB = (size_t)N * 128 * 4;
  const size_t HB = (size_t)N * 128 * 2;
  unsigned*       Z    = (unsigned*)(ws);
  unsigned short* Abf  = (unsigned short*)(ws + NB);
  unsigned short* Bbf  = (unsigned short*)(ws + NB + HB);
  float*    AB2  = (float*)(ws + NB + 2 * HB);
  unsigned* agg2 = (unsigned*)(ws + NB + 2 * HB + (size_t)N * 16);
  float*    wc0  = (float*)(ws + NB + 2 * HB + (size_t)N * 16 + (size_t)N * 8);
  float*    wc1  = wc0 + 128 * 256;
  float*    wc2  = wc1 + 128 * 256;

  const int nb = (N + 63) / 64;
  const int eb = (E + 63) / 64;
  const size_t nH = (size_t)N * 128;

  build_wcat<<<64, 256, 0, stream>>>(w1_0, wc0, 128, 128);
  build_wcat<<<64, 256, 0, stream>>>(w1_1, wc1, 128, 128);
  build_wcat<<<1, 256, 0, stream>>>(w1_2, wc2, 128, 2);

  // layer 0
  node_gemm<<<nb, 256, 0, stream>>>(x, wc0, b1_0, Abf, Bbf, N);
  fill_u32<<<1024, 256, 0, stream>>>(Z, KEY_NEGINF, nH);
  edge_mfma<<<eb, 256, 0, stream>>>(Abf, Bbf, ei, w2_0, b2_0, Z, E);
  decode_relu<<<1024, 256, 0, stream>>>(Z, nH);

  // layer 1
  node_gemm<<<nb, 256, 0, stream>>>((const float*)Z, wc1, b1_1, Abf, Bbf, N);
  fill_u32<<<1024, 256, 0, stream>>>(Z, KEY_NEGINF, nH);
  edge_mfma<<<eb, 256, 0, stream>>>(Abf, Bbf, ei, w2_1, b2_1, Z, E);
  decode_relu<<<1024, 256, 0, stream>>>(Z, nH);

  // layer 2
  node_thin<<<nb, 256, 0, stream>>>((const float*)Z, wc2, b1_2, AB2, N);
  fill_u32<<<256, 256, 0, stream>>>(agg2, KEY_NEGINF, (size_t)N * 2);
  edge_small<<<(E + 255) / 256, 256, 0, stream>>>(AB2, ei, w2_2, b2_2, agg2, E);
  final_out<<<((size_t)N * 2 + 255) / 256, 256, 0, stream>>>(agg2, (float*)d_out, (size_t)N * 2);
}

// Round 13
// 734.164 us; speedup vs baseline: 3.3527x; 1.1786x over previous
//
#include <hip/hip_runtime.h>
#include <cstdint>
#include <cstddef>

// ---------------------------------------------------------------------------
// EdgeCNN (DGCNN) 3-layer network. All GEMMs on MFMA (bf16 in, fp32 acc).
//   Factorization: concat[x_i, x_j-x_i] @ W1 = x_i@(W1a-W1b) + x_j@W1b
//   node_mfma: h @ wcat -> A (+b1), B planes (bf16), decode(keys)+ReLU fused.
//   edge_mfma: persistent blocks; per 64-edge tile: h=ReLU(A[dst]+B[src]) bf16
//     staged to LDS (reg-prefetched a tile ahead); msg = h @ W2bf via MFMA;
//     test-before-atomicMax of order-preserving keys into agg[dst].
// Weights pre-converted ONCE to bf16 transposed+swizzled buffers (wcg/wlg);
// R12 counters showed per-block W2 f2bf redundancy + latency-boundedness.
// Swizzle: 16B chunk c of row n stored at c^(n&7) (fixes 256B-row conflicts).
// Workspace ~52.6MB (< R7's proven overflow limit).
// ---------------------------------------------------------------------------

#define KEY_NEGINF 0x007FFFFFu  // fkey(-inf)

typedef __attribute__((ext_vector_type(8))) short bf16x8;
typedef __attribute__((ext_vector_type(4))) float f32x4;

__device__ __forceinline__ unsigned fkey(float f) {
  unsigned u = __float_as_uint(f);
  return (u & 0x80000000u) ? ~u : (u | 0x80000000u);
}
__device__ __forceinline__ float funkey(unsigned k) {
  unsigned u = (k & 0x80000000u) ? (k & 0x7FFFFFFFu) : ~k;
  return __uint_as_float(u);
}
__device__ __forceinline__ unsigned short f2bf(float f) {
  unsigned u = __float_as_uint(f);
  unsigned r = u + 0x7FFFu + ((u >> 16) & 1u);
  return (unsigned short)(r >> 16);
}
__device__ __forceinline__ float bflo(unsigned u) { return __uint_as_float(u << 16); }
__device__ __forceinline__ float bfhi(unsigned u) { return __uint_as_float(u & 0xFFFF0000u); }
__device__ __forceinline__ unsigned pack2(unsigned a, unsigned b) {
  float lo = fmaxf(bflo(a) + bflo(b), 0.f);
  float hi = fmaxf(bfhi(a) + bfhi(b), 0.f);
  return (unsigned)f2bf(lo) | ((unsigned)f2bf(hi) << 16);
}

// ---- weight prep (once per call) ----
// w1 [256k x 128o] fp32 -> wcg bf16 [256n][128k], n<128: W1a-W1b col n; n>=128: W1b col n-128
__global__ void build_wcatbf(const float* __restrict__ w1, unsigned short* __restrict__ wcg) {
  int i = blockIdx.x * 256 + threadIdx.x;  // 4096 = 256n x 16c
  if (i >= 256 * 16) return;
  int n = i >> 4, c = i & 15;
  alignas(16) unsigned short ob[8];
  #pragma unroll
  for (int j = 0; j < 8; ++j) {
    int k = c * 8 + j;
    float v;
    if (n < 128) v = w1[(size_t)k * 128 + n] - w1[(size_t)(128 + k) * 128 + n];
    else         v = w1[(size_t)(128 + k) * 128 + (n - 128)];
    ob[j] = f2bf(v);
  }
  *reinterpret_cast<uint4*>(&wcg[n * 128 + ((c ^ (n & 7)) * 8)]) =
      *reinterpret_cast<const uint4*>(ob);
}

// W2 [128k x 128n] fp32 -> wlg bf16 [128n][128k] swizzled
__global__ void build_w2bf(const float* __restrict__ w2, unsigned short* __restrict__ wlg) {
  int i = blockIdx.x * 256 + threadIdx.x;  // 2048 = 128n x 16c
  if (i >= 128 * 16) return;
  int n = i >> 4, c = i & 15;
  alignas(16) unsigned short ob[8];
  #pragma unroll
  for (int j = 0; j < 8; ++j) ob[j] = f2bf(w2[(size_t)(c * 8 + j) * 128 + n]);
  *reinterpret_cast<uint4*>(&wlg[n * 128 + ((c ^ (n & 7)) * 8)]) =
      *reinterpret_cast<const uint4*>(ob);
}

// layer-2 thin weights: wcat2 [128k][4] fp32 (cols 0,1 = W1a-W1b; 2,3 = W1b)
__global__ void build_wcat(const float* __restrict__ w1, float* __restrict__ wcat,
                           int F, int O) {
  int i = blockIdx.x * 256 + threadIdx.x;
  int total = F * O;
  if (i >= total) return;
  int k = i / O, o = i - k * O;
  float wa = w1[(size_t)k * O + o];
  float wb = w1[(size_t)(F + k) * O + o];
  wcat[(size_t)k * 2 * O + o] = wa - wb;
  wcat[(size_t)k * 2 * O + O + o] = wb;
}

__global__ void fill_u32(unsigned* __restrict__ p, unsigned v, size_t n) {
  size_t i = (size_t)blockIdx.x * blockDim.x + threadIdx.x;
  size_t stride = (size_t)gridDim.x * blockDim.x;
  for (; i < n; i += stride) p[i] = v;
}

__global__ void final_out(const unsigned* __restrict__ p, float* __restrict__ out, size_t n) {
  size_t i = (size_t)blockIdx.x * blockDim.x + threadIdx.x;
  size_t stride = (size_t)gridDim.x * blockDim.x;
  for (; i < n; i += stride) {
    unsigned k = p[i];
    out[i] = (k == KEY_NEGINF) ? 0.0f : funkey(k);
  }
}

// node MFMA: hin (fp32 x, or agg keys when decode=1) [N,128] @ wcat bf16 ->
// Abf (cols 0..127, +b1), Bbf (cols 128..255). Tile 64 nodes x 256 cols.
// LDS: at 16KB + wt 64KB = 80KB exactly -> 2 blocks/CU.
__global__ __launch_bounds__(256, 2) void node_mfma(
    const unsigned* __restrict__ hin, int decode,
    const unsigned short* __restrict__ wcg, const float* __restrict__ b1,
    unsigned short* __restrict__ Abf, unsigned short* __restrict__ Bbf, int nN) {
  __shared__ unsigned short at[64 * 128];
  __shared__ unsigned short wt[256 * 128];
  int t = threadIdx.x;
  {  // stage wt: 64KB verbatim (already transposed+swizzled)
    const uint4* src = reinterpret_cast<const uint4*>(wcg);
    uint4* dst = reinterpret_cast<uint4*>(wt);
    for (int i = t; i < 4096; i += 256) dst[i] = src[i];
  }
  int m_base = blockIdx.x * 64;
  {  // stage at: fp32/keys -> bf16, optional decode+ReLU, swizzled
    int r = t >> 2, q = t & 3;
    int gm = min(m_base + r, nN - 1);
    const uint4* src = reinterpret_cast<const uint4*>(hin + (size_t)gm * 128);
    #pragma unroll
    for (int j = 0; j < 4; ++j) {
      int c = q + 4 * j;
      uint4 u0 = src[c * 2], u1 = src[c * 2 + 1];
      unsigned b[8] = {u0.x, u0.y, u0.z, u0.w, u1.x, u1.y, u1.z, u1.w};
      alignas(16) unsigned short ob[8];
      #pragma unroll
      for (int e = 0; e < 8; ++e) {
        float v = decode ? fmaxf(funkey(b[e]), 0.f) : __uint_as_float(b[e]);
        ob[e] = f2bf(v);
      }
      *reinterpret_cast<uint4*>(&at[r * 128 + ((c ^ (r & 7)) * 8)]) =
          *reinterpret_cast<const uint4*>(ob);
    }
  }
  __syncthreads();

  int l = t & 63, w = t >> 6;
  int strip = w * 16, lr = l & 15, lh = l >> 4;
  int arow = strip + lr, erow = strip + lh * 4;

  bf16x8 af[4];
  #pragma unroll
  for (int ks = 0; ks < 4; ++ks)
    af[ks] = *reinterpret_cast<const bf16x8*>(
        &at[arow * 128 + (((ks * 4 + lh) ^ (arow & 7)) * 8)]);

  #pragma unroll
  for (int nt = 0; nt < 16; ++nt) {
    f32x4 acc = (f32x4){0.f, 0.f, 0.f, 0.f};
    int n = nt * 16 + lr;
    #pragma unroll
    for (int ks = 0; ks < 4; ++ks) {
      bf16x8 bf = *reinterpret_cast<const bf16x8*>(
          &wt[n * 128 + (((ks * 4 + lh) ^ (n & 7)) * 8)]);
      acc = __builtin_amdgcn_mfma_f32_16x16x32_bf16(af[ks], bf, acc, 0, 0, 0);
    }
    bool isA = (n < 128);
    float bias = isA ? b1[n] : 0.f;
    int coln = isA ? n : n - 128;
    unsigned short* plane = isA ? Abf : Bbf;
    #pragma unroll
    for (int j = 0; j < 4; ++j) {
      int gm = m_base + erow + j;
      if (gm < nN) plane[(size_t)gm * 128 + coln] = f2bf(acc[j] + bias);
    }
  }
}

// edge MFMA, persistent: grid ~768 blocks loop tiles of 64 edges.
// LDS: hs 16KB + wl 32KB + dstl -> 48.3KB => 3 blocks/CU.
// Pipeline: gathers for tile t+1 issued into regs before tile t's MFMA.
__global__ __launch_bounds__(256, 3) void edge_mfma(
    const unsigned short* __restrict__ Abf, const unsigned short* __restrict__ Bbf,
    const int* __restrict__ ei, const unsigned short* __restrict__ wlg,
    const float* __restrict__ b2, unsigned* __restrict__ aggk, int E_) {
  __shared__ unsigned short hs[64 * 128];
  __shared__ unsigned short wl[128 * 128];
  __shared__ int dstl[64];
  int t = threadIdx.x;
  {  // stage wl: 32KB verbatim
    const uint4* src = reinterpret_cast<const uint4*>(wlg);
    uint4* dst = reinterpret_cast<uint4*>(wl);
    for (int i = t; i < 2048; i += 256) dst[i] = src[i];
  }
  int l = t & 63, w = t >> 6;
  int strip = w * 16, lr = l & 15, lh = l >> 4;
  int arow = strip + lr, erow = strip + lh * 4;
  int r = t >> 2, q = t & 3;

  float bb[8];
  #pragma unroll
  for (int nt = 0; nt < 8; ++nt) bb[nt] = b2[nt * 16 + lr];

  int ntiles = (E_ + 63) >> 6;
  int tile = blockIdx.x;
  uint4 ga[4], gb[4];
  int nd = 0;
  if (tile < ntiles) {
    int e = min(tile * 64 + r, E_ - 1);
    int s = ei[e], d = ei[E_ + e];
    const uint4* Ar = reinterpret_cast<const uint4*>(Abf + (size_t)d * 128);
    const uint4* Br = reinterpret_cast<const uint4*>(Bbf + (size_t)s * 128);
    #pragma unroll
    for (int j = 0; j < 4; ++j) { ga[j] = Ar[q + 4 * j]; gb[j] = Br[q + 4 * j]; }
    nd = ei[E_ + min(tile * 64 + t, E_ - 1)];
  }

  for (; tile < ntiles; tile += gridDim.x) {
    __syncthreads();  // hs free (prev tile's reads done); wl staged (1st iter)
    #pragma unroll
    for (int j = 0; j < 4; ++j) {
      int c = q + 4 * j;
      uint4 o;
      o.x = pack2(ga[j].x, gb[j].x);
      o.y = pack2(ga[j].y, gb[j].y);
      o.z = pack2(ga[j].z, gb[j].z);
      o.w = pack2(ga[j].w, gb[j].w);
      *reinterpret_cast<uint4*>(&hs[r * 128 + ((c ^ (r & 7)) * 8)]) = o;
    }
    if (t < 64) dstl[t] = nd;
    __syncthreads();  // hs + dstl ready

    int next = tile + gridDim.x;
    if (next < ntiles) {  // prefetch next tile's gathers into regs
      int e = min(next * 64 + r, E_ - 1);
      int s = ei[e], d = ei[E_ + e];
      const uint4* Ar = reinterpret_cast<const uint4*>(Abf + (size_t)d * 128);
      const uint4* Br = reinterpret_cast<const uint4*>(Bbf + (size_t)s * 128);
      #pragma unroll
      for (int j = 0; j < 4; ++j) { ga[j] = Ar[q + 4 * j]; gb[j] = Br[q + 4 * j]; }
      nd = ei[E_ + min(next * 64 + t, E_ - 1)];
    }

    int drow[4];
    #pragma unroll
    for (int j = 0; j < 4; ++j) drow[j] = dstl[erow + j];
    unsigned cur[8][4];
    #pragma unroll
    for (int nt = 0; nt < 8; ++nt) {
      int col = nt * 16 + lr;
      #pragma unroll
      for (int j = 0; j < 4; ++j)
        cur[nt][j] = aggk[(size_t)drow[j] * 128 + col];
    }

    bf16x8 af[4];
    #pragma unroll
    for (int ks = 0; ks < 4; ++ks)
      af[ks] = *reinterpret_cast<const bf16x8*>(
          &hs[arow * 128 + (((ks * 4 + lh) ^ (arow & 7)) * 8)]);

    #pragma unroll
    for (int nt = 0; nt < 8; ++nt) {
      f32x4 acc = (f32x4){0.f, 0.f, 0.f, 0.f};
      int n = nt * 16 + lr;
      #pragma unroll
      for (int ks = 0; ks < 4; ++ks) {
        bf16x8 bf = *reinterpret_cast<const bf16x8*>(
            &wl[n * 128 + (((ks * 4 + lh) ^ (n & 7)) * 8)]);
        acc = __builtin_amdgcn_mfma_f32_16x16x32_bf16(af[ks], bf, acc, 0, 0, 0);
      }
      #pragma unroll
      for (int j = 0; j < 4; ++j) {
        unsigned key = fkey(acc[j] + bb[nt]);
        if (key > cur[nt][j])
          atomicMax(aggk + (size_t)drow[j] * 128 + n, key);
      }
    }
  }
}

// Layer 2: hin = agg keys [N,128]; decode+ReLU fused. @ wcat2 [128,4] -> AB2.
__global__ void node_thin(const unsigned* __restrict__ hin, const float* __restrict__ wcat2,
                          const float* __restrict__ b1, float* __restrict__ AB2,
                          int nNodes) {
  __shared__ float w[128 * 4];
  int t = threadIdx.x;
  if (t < 128) *reinterpret_cast<float4*>(&w[t * 4]) =
      reinterpret_cast<const float4*>(wcat2)[t];
  __syncthreads();
  int node = blockIdx.x * 64 + (t >> 2);
  int o = t & 3;
  if (node >= nNodes) return;
  const uint4* h4 = reinterpret_cast<const uint4*>(hin + (size_t)node * 128);
  float acc = 0.f;
  #pragma unroll 8
  for (int kk = 0; kk < 32; ++kk) {
    uint4 x = h4[kk];
    acc += fmaxf(funkey(x.x), 0.f) * w[(kk * 4 + 0) * 4 + o];
    acc += fmaxf(funkey(x.y), 0.f) * w[(kk * 4 + 1) * 4 + o];
    acc += fmaxf(funkey(x.z), 0.f) * w[(kk * 4 + 2) * 4 + o];
    acc += fmaxf(funkey(x.w), 0.f) * w[(kk * 4 + 3) * 4 + o];
  }
  if (o < 2) acc += b1[o];
  AB2[(size_t)node * 4 + o] = acc;
}

__global__ void edge_small(const float* __restrict__ AB2, const int* __restrict__ ei,
                           const float* __restrict__ w2, const float* __restrict__ b2,
                           unsigned* __restrict__ aggk2, int E_) {
  int e = blockIdx.x * 256 + threadIdx.x;
  if (e >= E_) return;
  int s = ei[e];
  int d = ei[E_ + e];
  float2 a = *reinterpret_cast<const float2*>(AB2 + (size_t)d * 4);
  float2 b = *reinterpret_cast<const float2*>(AB2 + (size_t)s * 4 + 2);
  float h0 = fmaxf(a.x + b.x, 0.f);
  float h1 = fmaxf(a.y + b.y, 0.f);
  float m0 = h0 * w2[0] + h1 * w2[2] + b2[0];
  float m1 = h0 * w2[1] + h1 * w2[3] + b2[1];
  atomicMax(aggk2 + (size_t)d * 2 + 0, fkey(m0));
  atomicMax(aggk2 + (size_t)d * 2 + 1, fkey(m1));
}

extern "C" void kernel_launch(void* const* d_in, const int* in_sizes, int n_in,
                              void* d_out, int out_size, void* d_ws, size_t ws_size,
                              hipStream_t stream) {
  const float* x    = (const float*)d_in[0];
  const int*   ei   = (const int*)d_in[1];
  const float* w1_0 = (const float*)d_in[2];
  const float* b1_0 = (const float*)d_in[3];
  const float* w2_0 = (const float*)d_in[4];
  const float* b2_0 = (const float*)d_in[5];
  const float* w1_1 = (const float*)d_in[6];
  const float* b1_1 = (const float*)d_in[7];
  const float* w2_1 = (const float*)d_in[8];
  const float* b2_1 = (const float*)d_in[9];
  const float* w1_2 = (const float*)d_in[10];
  const float* b1_2 = (const float*)d_in[11];
  const float* w2_2 = (const float*)d_in[12];
  const float* b2_2 = (const float*)d_in[13];

  const int N = in_sizes[0] / 128;
  const int E = in_sizes[1] / 2;

  // Workspace ~52.6 MB (< R7 overflow limit):
  char* ws = (char*)d_ws;
  const size_t NB = (size_t)N * 128 * 4;  // 25.6 MB
  const size_t HB = (size_t)N * 128 * 2;  // 12.8 MB
  unsigned*       Z    = (unsigned*)(ws);
  unsigned short* Abf  = (unsigned short*)(ws + NB);
  unsigned short* Bbf  = (unsigned short*)(ws + NB + HB);
  float*    AB2  = (float*)(ws + NB + 2 * HB);
  unsigned* agg2 = (unsigned*)(ws + NB + 2 * HB + (size_t)N * 16);
  char*     wp   = ws + NB + 2 * HB + (size_t)N * 16 + (size_t)N * 8;
  unsigned short* wcg0 = (unsigned short*)(wp);                // 64 KB
  unsigned short* wcg1 = (unsigned short*)(wp + 65536);        // 64 KB
  unsigned short* wlg0 = (unsigned short*)(wp + 131072);       // 32 KB
  unsigned short* wlg1 = (unsigned short*)(wp + 163840);       // 32 KB
  float*          wc2  = (float*)(wp + 196608);                // 2 KB

  const int nb = (N + 63) / 64;
  const int eb = (E + 63) / 64;
  const int egrid = eb < 768 ? eb : 768;
  const size_t nH = (size_t)N * 128;

  build_wcatbf<<<16, 256, 0, stream>>>(w1_0, wcg0);
  build_wcatbf<<<16, 256, 0, stream>>>(w1_1, wcg1);
  build_w2bf<<<8, 256, 0, stream>>>(w2_0, wlg0);
  build_w2bf<<<8, 256, 0, stream>>>(w2_1, wlg1);
  build_wcat<<<1, 256, 0, stream>>>(w1_2, wc2, 128, 2);

  // layer 0
  node_mfma<<<nb, 256, 0, stream>>>((const unsigned*)x, 0, wcg0, b1_0, Abf, Bbf, N);
  fill_u32<<<1024, 256, 0, stream>>>(Z, KEY_NEGINF, nH);
  edge_mfma<<<egrid, 256, 0, stream>>>(Abf, Bbf, ei, wlg0, b2_0, Z, E);

  // layer 1 (node_mfma decodes Z keys on load; Z refilled after)
  node_mfma<<<nb, 256, 0, stream>>>(Z, 1, wcg1, b1_1, Abf, Bbf, N);
  fill_u32<<<1024, 256, 0, stream>>>(Z, KEY_NEGINF, nH);
  edge_mfma<<<egrid, 256, 0, stream>>>(Abf, Bbf, ei, wlg1, b2_1, Z, E);

  // layer 2 (node_thin decodes Z keys on load)
  node_thin<<<nb, 256, 0, stream>>>(Z, wc2, b1_2, AB2, N);
  fill_u32<<<256, 256, 0, stream>>>(agg2, KEY_NEGINF, (size_t)N * 2);
  edge_small<<<(E + 255) / 256, 256, 0, stream>>>(AB2, ei, w2_2, b2_2, agg2, E);
  final_out<<<((size_t)N * 2 + 255) / 256, 256, 0, stream>>>(agg2, (float*)d_out, (size_t)N * 2);
}